// Round 3
// baseline (1160.026 us; speedup 1.0000x reference)
//
#include <hip/hip_runtime.h>
#include <cmath>

// Problem constants (fixed by the reference; active_size input == 512)
#define NB   32768
#define DIN  128
#define DMAX 1024
#define A    512

// ws layout (floats):
//   [0, 65536)              WinT [128 k][512 n]  = W_in[n][k]
//   [65536 + g*65536, ...)  WgT_g[128 k][512 n]  = W_gate[g*512+n][k],  g=0,1,2

__global__ __launch_bounds__(256) void transpose_w(
    const float* __restrict__ Win, const float* __restrict__ Wg,
    float* __restrict__ ws)
{
    int idx = blockIdx.x * 256 + threadIdx.x;   // 262144 total
    int m = idx >> 16;                           // 0 = Win, 1..3 = gate g = m-1
    int r = idx & 65535;
    int k = r >> 9;                              // 0..127
    int n = r & 511;                             // 0..511
    float v = (m == 0) ? Win[n * DIN + k]
                       : Wg[(((m - 1) << 9) + n) * DIN + k];
    ws[idx] = v;
}

__device__ __forceinline__ float sigm(float x) { return 1.0f / (1.0f + expf(-x)); }

// Wave-level microkernel: each wave computes 64 batch rows (lane = row) x 32 cols.
// A staged in LDS (1 ds_read_b128 per 4 k per lane -> LDS pipe ~5% utilized).
// B read with wave-uniform addresses from const __restrict__ memory -> scalar
// loads feeding v_fmac_f32's SGPR operand; no LDS, no VGPR cost for B.
// __launch_bounds__(256,2): VGPR cap 256 — round 2's (256,4) forced a 64-VGPR
// allocation and spilled the 64 accumulators to scratch (+250 MB WRITE_SIZE).
__global__ __launch_bounds__(256, 2) void gser_main(
    const float* __restrict__ X,    // [NB, DIN]
    const float* __restrict__ P,    // [NB, DMAX]
    const float* __restrict__ Wres, // [DMAX, DMAX], use [k<512][j<512]
    const float* __restrict__ wsW,  // WinT + WgT (see layout above)
    const float* __restrict__ lrp,  // [DMAX]
    const float* __restrict__ stp,  // [DMAX]
    float* __restrict__ out)        // [NB, DMAX]
{
    __shared__ float As[64][68];    // 64 rows x 64 k, stride 68 floats (16B aligned)

    const int t    = threadIdx.x;
    const int lane = t & 63;
    const int wid  = __builtin_amdgcn_readfirstlane(t >> 6);  // force SGPR
    const int m0   = blockIdx.y * 64;
    const int j0   = blockIdx.x * 128;
    const int jw   = j0 + wid * 32;   // this wave's 32-col window (SGPR)

    float acc[32];
#pragma unroll
    for (int i = 0; i < 32; ++i) acc[i] = 0.f;

    // ---- stage one 64x64 A-chunk into LDS ----
    auto stage = [&](const float* Asrc, int lda) {
        __syncthreads();
        const int row = t >> 2;       // 0..63
        const int c0  = t & 3;
        const float4* g = reinterpret_cast<const float4*>(Asrc + (size_t)row * lda);
#pragma unroll
        for (int q = 0; q < 4; ++q) {
            float4 v = g[c0 + q * 4];
            *reinterpret_cast<float4*>(&As[row][(c0 + q * 4) * 4]) = v;
        }
        __syncthreads();
    };

    // ---- accumulate 64 k-steps: acc[n] += A[lane][k] * B[k][jw+n] ----
    auto accum = [&](const float* Bsrc, int ldb, float* ac) {
        for (int k4 = 0; k4 < 16; ++k4) {
            float4 a4 = *reinterpret_cast<const float4*>(&As[lane][k4 * 4]);
#pragma unroll
            for (int u = 0; u < 4; ++u) {
                const float a = (&a4.x)[u];
                const float* br = Bsrc + (size_t)(k4 * 4 + u) * ldb + jw;  // wave-uniform
#pragma unroll
                for (int j4 = 0; j4 < 8; ++j4) {
                    float4 b = *reinterpret_cast<const float4*>(br + j4 * 4);
                    ac[j4 * 4 + 0] = fmaf(a, b.x, ac[j4 * 4 + 0]);
                    ac[j4 * 4 + 1] = fmaf(a, b.y, ac[j4 * 4 + 1]);
                    ac[j4 * 4 + 2] = fmaf(a, b.z, ac[j4 * 4 + 2]);
                    ac[j4 * 4 + 3] = fmaf(a, b.w, ac[j4 * 4 + 3]);
                }
            }
        }
    };

    // ---- main: reservoir part, K = 512 (A from P, B from Wres[k][j]) ----
    for (int c = 0; c < 8; ++c) {
        stage(P + (size_t)m0 * DMAX + c * 64, DMAX);
        accum(Wres + (size_t)(c * 64) * DMAX, DMAX, acc);
    }
    // ---- main: input part, K = 128 (A from X, B from WinT) ----
    for (int c = 0; c < 2; ++c) {
        stage(X + (size_t)m0 * DIN + c * 64, DIN);
        accum(wsW + (size_t)(c * 64) * 512, 512, acc);
    }
    // acc now holds s1 = input_part + reservoir_part

    float accg[32];

    // ---- i gate: acc = tanh(sigmoid(accg) * acc) ----
#pragma unroll
    for (int i = 0; i < 32; ++i) accg[i] = 0.f;
    for (int c = 0; c < 2; ++c) {
        stage(X + (size_t)m0 * DIN + c * 64, DIN);
        accum(wsW + 65536 + 0 * 65536 + (size_t)(c * 64) * 512, 512, accg);
    }
#pragma unroll
    for (int i = 0; i < 32; ++i) acc[i] = tanhf(sigm(accg[i]) * acc[i]);

    // ---- f gate: acc = (1-leak)*fg*prev + leak*acc ----
#pragma unroll
    for (int i = 0; i < 32; ++i) accg[i] = 0.f;
    for (int c = 0; c < 2; ++c) {
        stage(X + (size_t)m0 * DIN + c * 64, DIN);
        accum(wsW + 65536 + 1 * 65536 + (size_t)(c * 64) * 512, 512, accg);
    }
    {
        const float* prow = P + (size_t)(m0 + lane) * DMAX + jw;
#pragma unroll
        for (int j4 = 0; j4 < 8; ++j4) {
            float4 pv = *reinterpret_cast<const float4*>(prow + j4 * 4);
#pragma unroll
            for (int c = 0; c < 4; ++c) {
                const int i = j4 * 4 + c;
                const float lk = sigm(lrp[jw + i]);           // uniform -> scalar load
                const float fg = sigm(accg[i]);
                acc[i] = (1.0f - lk) * (fg * (&pv.x)[c]) + lk * acc[i];
            }
        }
    }

    // ---- o gate: st = sigmoid(accg)*acc; spike threshold; store ----
#pragma unroll
    for (int i = 0; i < 32; ++i) accg[i] = 0.f;
    for (int c = 0; c < 2; ++c) {
        stage(X + (size_t)m0 * DIN + c * 64, DIN);
        accum(wsW + 65536 + 2 * 65536 + (size_t)(c * 64) * 512, 512, accg);
    }
    {
        const size_t orow = (size_t)(m0 + lane) * DMAX;
#pragma unroll
        for (int j4 = 0; j4 < 8; ++j4) {
            float4 res;
#pragma unroll
            for (int c = 0; c < 4; ++c) {
                const int i = j4 * 4 + c;
                const float thr = log1pf(expf(stp[jw + i]));  // softplus, uniform
                float st = sigm(accg[i]) * acc[i];
                st = (st > thr) ? (st - thr) : st;
                (&res.x)[c] = st;
            }
            *reinterpret_cast<float4*>(out + orow + jw + j4 * 4) = res;
        }
        // zero-pad cols [512, 1024): this wave covers 512+jw .. 512+jw+31
        float4 z; z.x = 0.f; z.y = 0.f; z.z = 0.f; z.w = 0.f;
#pragma unroll
        for (int j4 = 0; j4 < 8; ++j4)
            *reinterpret_cast<float4*>(out + orow + A + jw + j4 * 4) = z;
    }
}

extern "C" void kernel_launch(void* const* d_in, const int* in_sizes, int n_in,
                              void* d_out, int out_size, void* d_ws, size_t ws_size,
                              hipStream_t stream) {
    const float* X    = (const float*)d_in[0];
    const float* P    = (const float*)d_in[1];
    const float* Wres = (const float*)d_in[2];
    const float* Win  = (const float*)d_in[3];
    const float* Wg   = (const float*)d_in[4];
    const float* lrp  = (const float*)d_in[5];
    const float* stp  = (const float*)d_in[6];
    float* out = (float*)d_out;
    float* ws  = (float*)d_ws;

    // 1) transpose W_in / W_gate into ws (k-major panels for scalar B loads)
    hipLaunchKernelGGL(transpose_w, dim3(1024), dim3(256), 0, stream, Win, Wg, ws);
    // 2) fused GEMM + gating
    hipLaunchKernelGGL(gser_main, dim3(4, 512), dim3(256), 0, stream,
                       X, P, Wres, ws, lrp, stp, out);
}

// Round 4
// 447.288 us; speedup vs baseline: 2.5935x; 2.5935x over previous
//
#include <hip/hip_runtime.h>
#include <cmath>

// Problem constants (fixed by the reference; active_size == 512)
#define NB   32768
#define DIN  128
#define DMAX 1024
#define A    512

typedef _Float16 half8 __attribute__((ext_vector_type(8)));
typedef float f32x4 __attribute__((ext_vector_type(4)));

// ws layout in halves (_Float16), total 1048576 halves = 2 MB:
//  [WS_RES_H, +262144) : Wres^T hi, tiled as 64 chunks (jb*16+kc) of [128 j][32 k]
//  [WS_RES_L, +262144) : Wres^T lo, same tiling
//  [WS_PAN + p*131072, +65536)        : panel p hi (p=0 Win, 1..3 gates), chunks (jb*4+kc)
//  [WS_PAN + p*131072 + 65536, ...)   : panel p lo
#define WS_RES_H 0
#define WS_RES_L 262144
#define WS_PAN   524288

// Pre-pass: transpose + fp16 hi/lo split of all weight panels into ws.
// hi = fp16(v), lo = fp16(v - hi): |v - hi - lo| <= 2^-24 |v|  (fp32-equivalent
// when combined with 3-product MFMA accumulation in fp32).
__global__ __launch_bounds__(256) void split_weights(
    const float* __restrict__ Wres, const float* __restrict__ Win,
    const float* __restrict__ Wg, _Float16* __restrict__ ws)
{
    int idx = blockIdx.x * 256 + threadIdx.x;  // 0 .. 524287
    if (idx < 262144) {
        int k = idx >> 9, j = idx & 511;
        float v = Wres[k * DMAX + j];
        _Float16 h = (_Float16)v;
        _Float16 l = (_Float16)(v - (float)h);
        int off = ((j >> 7) * 16 + (k >> 5)) * 4096 + (j & 127) * 32 + (k & 31);
        ws[WS_RES_H + off] = h;
        ws[WS_RES_L + off] = l;
    } else {
        int r = idx - 262144;        // 0..262143
        int p = r >> 16;             // 0..3 : Win, gate_i, gate_f, gate_o
        int q = r & 65535;
        int j = q >> 7, k = q & 127;
        float v = (p == 0) ? Win[j * DIN + k]
                           : Wg[((p - 1) * 512 + j) * DIN + k];
        _Float16 h = (_Float16)v;
        _Float16 l = (_Float16)(v - (float)h);
        int off = ((j >> 7) * 4 + (k >> 5)) * 4096 + (j & 127) * 32 + (k & 31);
        ws[WS_PAN + p * 131072 + off] = h;
        ws[WS_PAN + p * 131072 + 65536 + off] = l;
    }
}

__device__ __forceinline__ float sigm(float x) { return 1.0f / (1.0f + expf(-x)); }

// Fused split-fp16 MFMA kernel.
// Block: 128 m x 128 j tile, 256 threads = 4 waves in 2x2; wave tile 64x64 as
// 4x4 of mfma_f32_16x16x32_f16. Split products hh+hl+lh accumulate into the
// same fp32 acc. Frag layouts (m89/m97-verified): A[m=lane&15][k=(lane>>4)*8+i],
// B[n=lane&15][k=(lane>>4)*8+i], C/D col=lane&15, row=(lane>>4)*4+reg.
__global__ __launch_bounds__(256, 2) void gser_mfma(
    const float* __restrict__ X,    // [NB, DIN]
    const float* __restrict__ P,    // [NB, DMAX]
    const _Float16* __restrict__ ws,
    const float* __restrict__ lrp, const float* __restrict__ stp,
    float* __restrict__ out)        // [NB, DMAX]
{
    // stride 40 halves = 80 B: 16B-aligned rows; frag reads land 2-way (free)
    __shared__ _Float16 Ah[128][40], Al[128][40], Bh[128][40], Bl[128][40];

    const int t    = threadIdx.x;
    const int lane = t & 63;
    const int w    = t >> 6;
    const int wm   = w & 1, wn = w >> 1;
    const int quad = lane >> 4, l16 = lane & 15;
    const int jb   = blockIdx.x;          // 0..3
    const int m0   = blockIdx.y * 128;
    const int j0   = jb * 128;

    const int sm = t >> 1;                // A staging: row 0..127
    const int sk = (t & 1) * 16;          // A staging: k offset 0/16

    auto stageA = [&](const float* src, int lda, int k0) {
        const float* p = src + (size_t)sm * lda + k0 + sk;
        float4 f0 = *(const float4*)(p);
        float4 f1 = *(const float4*)(p + 4);
        float4 f2 = *(const float4*)(p + 8);
        float4 f3 = *(const float4*)(p + 12);
        float fv[16] = {f0.x,f0.y,f0.z,f0.w, f1.x,f1.y,f1.z,f1.w,
                        f2.x,f2.y,f2.z,f2.w, f3.x,f3.y,f3.z,f3.w};
        half8 hh0, hh1, ll0, ll1;
#pragma unroll
        for (int i = 0; i < 8; ++i) {
            _Float16 h = (_Float16)fv[i];
            hh0[i] = h; ll0[i] = (_Float16)(fv[i] - (float)h);
        }
#pragma unroll
        for (int i = 0; i < 8; ++i) {
            _Float16 h = (_Float16)fv[8 + i];
            hh1[i] = h; ll1[i] = (_Float16)(fv[8 + i] - (float)h);
        }
        *(half8*)&Ah[sm][sk]     = hh0;
        *(half8*)&Ah[sm][sk + 8] = hh1;
        *(half8*)&Al[sm][sk]     = ll0;
        *(half8*)&Al[sm][sk + 8] = ll1;
    };

    auto stageB = [&](const _Float16* chH, const _Float16* chL) {
#pragma unroll
        for (int r = 0; r < 2; ++r) {
            int s  = t + r * 256;
            int bj = s >> 2, bk = (s & 3) * 8;
            *(half8*)&Bh[bj][bk] = *(const half8*)(chH + s * 8);  // coalesced
            *(half8*)&Bl[bj][bk] = *(const half8*)(chL + s * 8);
        }
    };

    auto mmac = [&](f32x4 (&C)[4][4]) {
        half8 fah[4], fal[4];
#pragma unroll
        for (int ms = 0; ms < 4; ++ms) {
            int row = wm * 64 + ms * 16 + l16;
            fah[ms] = *(const half8*)&Ah[row][quad * 8];
            fal[ms] = *(const half8*)&Al[row][quad * 8];
        }
#pragma unroll
        for (int js = 0; js < 4; ++js) {
            int col = wn * 64 + js * 16 + l16;
            half8 fbh = *(const half8*)&Bh[col][quad * 8];
            half8 fbl = *(const half8*)&Bl[col][quad * 8];
#pragma unroll
            for (int ms = 0; ms < 4; ++ms) {
                C[ms][js] = __builtin_amdgcn_mfma_f32_16x16x32_f16(fah[ms], fbh, C[ms][js], 0, 0, 0);
                C[ms][js] = __builtin_amdgcn_mfma_f32_16x16x32_f16(fah[ms], fbl, C[ms][js], 0, 0, 0);
                C[ms][js] = __builtin_amdgcn_mfma_f32_16x16x32_f16(fal[ms], fbh, C[ms][js], 0, 0, 0);
            }
        }
    };

    f32x4 accS[4][4];
#pragma unroll
    for (int i = 0; i < 4; ++i)
#pragma unroll
        for (int j = 0; j < 4; ++j)
            accS[i][j] = (f32x4){0.f, 0.f, 0.f, 0.f};

    // ---- phase R: K=512, A = prev, B = Wres^T (split) ----
    const float* Pblk = P + (size_t)m0 * DMAX;
    for (int kc = 0; kc < 16; ++kc) {
        __syncthreads();
        stageA(Pblk, DMAX, kc * 32);
        const _Float16* ch = ws + WS_RES_H + (size_t)(jb * 16 + kc) * 4096;
        const _Float16* cl = ws + WS_RES_L + (size_t)(jb * 16 + kc) * 4096;
        stageB(ch, cl);
        __syncthreads();
        mmac(accS);
    }

    // ---- phase G pass 0: W_in (K=128) accumulated into accS -> s1 ----
    const float* Xblk = X + (size_t)m0 * DIN;
    for (int kc = 0; kc < 4; ++kc) {
        __syncthreads();
        stageA(Xblk, DIN, kc * 32);
        const _Float16* base = ws + WS_PAN + 0 * 131072;
        stageB(base + (size_t)(jb * 4 + kc) * 4096,
               base + 65536 + (size_t)(jb * 4 + kc) * 4096);
        __syncthreads();
        mmac(accS);
    }

    f32x4 accG[4][4];

    // ---- pass 1: i gate; accS = tanh(sigm(g) * accS) ----
#pragma unroll
    for (int i = 0; i < 4; ++i)
#pragma unroll
        for (int j = 0; j < 4; ++j)
            accG[i][j] = (f32x4){0.f, 0.f, 0.f, 0.f};
    for (int kc = 0; kc < 4; ++kc) {
        __syncthreads();
        stageA(Xblk, DIN, kc * 32);
        const _Float16* base = ws + WS_PAN + 1 * 131072;
        stageB(base + (size_t)(jb * 4 + kc) * 4096,
               base + 65536 + (size_t)(jb * 4 + kc) * 4096);
        __syncthreads();
        mmac(accG);
    }
#pragma unroll
    for (int ms = 0; ms < 4; ++ms)
#pragma unroll
        for (int js = 0; js < 4; ++js)
#pragma unroll
            for (int r = 0; r < 4; ++r)
                accS[ms][js][r] = tanhf(sigm(accG[ms][js][r]) * accS[ms][js][r]);

    // ---- pass 2: f gate; accS = (1-leak)*(fg*prev) + leak*accS ----
#pragma unroll
    for (int i = 0; i < 4; ++i)
#pragma unroll
        for (int j = 0; j < 4; ++j)
            accG[i][j] = (f32x4){0.f, 0.f, 0.f, 0.f};
    for (int kc = 0; kc < 4; ++kc) {
        __syncthreads();
        stageA(Xblk, DIN, kc * 32);
        const _Float16* base = ws + WS_PAN + 2 * 131072;
        stageB(base + (size_t)(jb * 4 + kc) * 4096,
               base + 65536 + (size_t)(jb * 4 + kc) * 4096);
        __syncthreads();
        mmac(accG);
    }
    {
        float lk[4];
#pragma unroll
        for (int js = 0; js < 4; ++js)
            lk[js] = sigm(lrp[j0 + wn * 64 + js * 16 + l16]);
#pragma unroll
        for (int ms = 0; ms < 4; ++ms)
#pragma unroll
            for (int r = 0; r < 4; ++r) {
                int row = m0 + wm * 64 + ms * 16 + quad * 4 + r;
#pragma unroll
                for (int js = 0; js < 4; ++js) {
                    int col = j0 + wn * 64 + js * 16 + l16;
                    float pv = P[(size_t)row * DMAX + col];
                    float fg = sigm(accG[ms][js][r]);
                    accS[ms][js][r] = (1.0f - lk[js]) * (fg * pv) + lk[js] * accS[ms][js][r];
                }
            }
    }

    // ---- pass 3: o gate; st = sigm(g)*accS; spike threshold; store ----
#pragma unroll
    for (int i = 0; i < 4; ++i)
#pragma unroll
        for (int j = 0; j < 4; ++j)
            accG[i][j] = (f32x4){0.f, 0.f, 0.f, 0.f};
    for (int kc = 0; kc < 4; ++kc) {
        __syncthreads();
        stageA(Xblk, DIN, kc * 32);
        const _Float16* base = ws + WS_PAN + 3 * 131072;
        stageB(base + (size_t)(jb * 4 + kc) * 4096,
               base + 65536 + (size_t)(jb * 4 + kc) * 4096);
        __syncthreads();
        mmac(accG);
    }
    {
        float thr[4];
#pragma unroll
        for (int js = 0; js < 4; ++js)
            thr[js] = log1pf(expf(stp[j0 + wn * 64 + js * 16 + l16]));
#pragma unroll
        for (int ms = 0; ms < 4; ++ms)
#pragma unroll
            for (int r = 0; r < 4; ++r) {
                int row = m0 + wm * 64 + ms * 16 + quad * 4 + r;
#pragma unroll
                for (int js = 0; js < 4; ++js) {
                    int col = j0 + wn * 64 + js * 16 + l16;
                    float st = sigm(accG[ms][js][r]) * accS[ms][js][r];
                    st = (st > thr[js]) ? (st - thr[js]) : st;
                    out[(size_t)row * DMAX + col] = st;
                }
            }
    }

    // ---- zero-pad cols [512,1024): this block covers [512 + jb*128, +128) ----
#pragma unroll
    for (int i = 0; i < 16; ++i) {
        int s  = t + i * 256;
        int rr = s >> 5, c4 = s & 31;
        *(float4*)(out + (size_t)(m0 + rr) * DMAX + A + jb * 128 + c4 * 4) =
            (float4){0.f, 0.f, 0.f, 0.f};
    }
}

extern "C" void kernel_launch(void* const* d_in, const int* in_sizes, int n_in,
                              void* d_out, int out_size, void* d_ws, size_t ws_size,
                              hipStream_t stream) {
    const float* X    = (const float*)d_in[0];
    const float* P    = (const float*)d_in[1];
    const float* Wres = (const float*)d_in[2];
    const float* Win  = (const float*)d_in[3];
    const float* Wg   = (const float*)d_in[4];
    const float* lrp  = (const float*)d_in[5];
    const float* stp  = (const float*)d_in[6];
    float* out = (float*)d_out;
    _Float16* ws = (_Float16*)d_ws;   // uses 2 MB

    hipLaunchKernelGGL(split_weights, dim3(2048), dim3(256), 0, stream,
                       Wres, Win, Wg, ws);
    hipLaunchKernelGGL(gser_mfma, dim3(4, 256), dim3(256), 0, stream,
                       X, P, ws, lrp, stp, out);
}